// Round 1
// baseline (61.106 us; speedup 1.0000x reference)
//
#include <hip/hip_runtime.h>
#include <hip/hip_bf16.h>
#include <math.h>

#define SIGMA_MAJORANT 0.1f
#define PI_F 3.14159265358979323846f

// env_map: [1,3,16,32] -> env[c*H*W + y*W + x], H=16, W=32
__global__ __launch_bounds__(256) void nerf_env_kernel(
    const float* __restrict__ rays_o,
    const float* __restrict__ rays_d,
    const float* __restrict__ env,
    float* __restrict__ out,
    int N)
{
    int i = blockIdx.x * blockDim.x + threadIdx.x;
    if (i >= N) return;

    const float ox = rays_o[3 * i + 0];
    const float oy = rays_o[3 * i + 1];
    const float oz = rays_o[3 * i + 2];
    const float dx = rays_d[3 * i + 0];
    const float dy = rays_d[3 * i + 1];
    const float dz = rays_d[3 * i + 2];

    const float a = dx * dx + dy * dy + dz * dz;
    const float c = ox * ox + oy * oy + oz * oz - 1.0f;  // BOUND^2 = 1
    const float b = 2.0f * (ox * dx + oy * dy + oz * dz);
    const float delta = b * b - 4.0f * a * c;
    const float sd = sqrtf(delta > 0.0f ? delta : 1.0f);
    const float t = (-b + sd) / (2.0f * a);
    const bool valid = (delta > 0.0f) && (t >= 0.0f);

    const float hx = ox + dx * t;
    const float hy = oy + dy * t;
    const float hz = oz + dz * t;

    // grid y coordinate: theta = atan2(x, -z) / pi
    float gy = atan2f(hx, -hz) / PI_F;
    if (isnan(gy)) gy = 0.0f;  // nan_to_num
    // grid x coordinate: phi = (2/pi)*acos(clip(y, -1+1e-6, 1-1e-6)) - 1
    float yc = hy;
    yc = fminf(fmaxf(yc, -1.0f + 1e-6f), 1.0f - 1e-6f);
    const float gx = (2.0f / PI_F) * acosf(yc) - 1.0f;

    // grid_sample, align_corners=False, padding zeros. H=16, W=32.
    const int H = 16, W = 32;
    const float ix = ((gx + 1.0f) * (float)W - 1.0f) * 0.5f;
    const float iy = ((gy + 1.0f) * (float)H - 1.0f) * 0.5f;
    const float ix0f = floorf(ix);
    const float iy0f = floorf(iy);
    const float wx1 = ix - ix0f;
    const float wy1 = iy - iy0f;
    const float wx0 = 1.0f - wx1;
    const float wy0 = 1.0f - wy1;

    const int ix0 = (int)ix0f;
    const int iy0 = (int)iy0f;
    const int ix1 = ix0 + 1;
    const int iy1 = iy0 + 1;

    const bool bx0 = (ix0 >= 0) && (ix0 <= W - 1);
    const bool bx1 = (ix1 >= 0) && (ix1 <= W - 1);
    const bool by0 = (iy0 >= 0) && (iy0 <= H - 1);
    const bool by1 = (iy1 >= 0) && (iy1 <= H - 1);

    const int cx0 = min(max(ix0, 0), W - 1);
    const int cx1 = min(max(ix1, 0), W - 1);
    const int cy0 = min(max(iy0, 0), H - 1);
    const int cy1 = min(max(iy1, 0), H - 1);

    const float w00 = wx0 * wy0 * ((bx0 && by0) ? 1.0f : 0.0f);
    const float w10 = wx1 * wy0 * ((bx1 && by0) ? 1.0f : 0.0f);
    const float w01 = wx0 * wy1 * ((bx0 && by1) ? 1.0f : 0.0f);
    const float w11 = wx1 * wy1 * ((bx1 && by1) ? 1.0f : 0.0f);

    const float atten = valid ? expf(-SIGMA_MAJORANT * t) : 0.0f;

    #pragma unroll
    for (int ch = 0; ch < 3; ++ch) {
        const float* plane = env + ch * H * W;
        const float v = plane[cy0 * W + cx0] * w00
                      + plane[cy0 * W + cx1] * w10
                      + plane[cy1 * W + cx0] * w01
                      + plane[cy1 * W + cx1] * w11;
        out[3 * i + ch] = atten * expf(v);
    }
}

extern "C" void kernel_launch(void* const* d_in, const int* in_sizes, int n_in,
                              void* d_out, int out_size, void* d_ws, size_t ws_size,
                              hipStream_t stream) {
    const float* rays_o = (const float*)d_in[0];
    const float* rays_d = (const float*)d_in[1];
    const float* env    = (const float*)d_in[2];
    float* out = (float*)d_out;
    const int N = in_sizes[0] / 3;  // 16384

    const int block = 256;
    const int grid = (N + block - 1) / block;
    nerf_env_kernel<<<grid, block, 0, stream>>>(rays_o, rays_d, env, out, N);
}